// Round 8
// baseline (100.442 us; speedup 1.0000x reference)
//
#include <hip/hip_runtime.h>
#include <type_traits>

typedef short bf16x8 __attribute__((ext_vector_type(8)));
typedef float f32x4 __attribute__((ext_vector_type(4)));

// ---------------- problem constants ----------------
constexpr int Hh = 14, Ww = 14, Cc = 512, Bb = 512, NR = 70, PadR = 80;
constexpr int MROWS = 72;   // LDS rows for m: 70 data + 2 zero rows (72..79 remapped)

// ---------------- constexpr replication of _crop_boxes ----------------
struct Box { int y1, y2, x1, x2; };

constexpr double cfloor(double v) { return (double)(long long)v; }  // v >= 0 only
constexpr double cround(double v) {  // np.round: half-to-even
    double f = cfloor(v);
    double fr = v - f;
    if (fr > 0.5) return f + 1.0;
    if (fr < 0.5) return f;
    return (((long long)f) & 1LL) ? f + 1.0 : f;
}

struct BoxArr { Box b[NR]; };

constexpr BoxArr make_boxes() {
    BoxArr out{};
    double rx_[14] = {}, ry_[14] = {}, wl_[14] = {};
    int nr = 0;
    for (int l = 1; l <= 3; ++l) {
        double wl  = cfloor(2.0 * 14.0 / (double)(l + 1));
        double wl2 = cfloor(wl / 2.0 - 1.0);
        double bb  = (l > 1) ? (14.0 - wl) / (double)(l - 1) : 0.0;
        double cen[3] = {};
        for (int k = 0; k < l; ++k) cen[k] = cfloor(wl2 + (double)k * bb) - wl2;
        for (int i = 0; i < l; ++i)
            for (int j = 0; j < l; ++j) { rx_[nr] = cen[j]; ry_[nr] = cen[i]; wl_[nr] = wl; ++nr; }
    }
    int nb = 0;
    for (int r = 0; r < nr; ++r) {
        for (int p = 1; p <= 2; ++p) {
            double len = wl_[r] / (double)p;
            for (int ix = 0; ix < p; ++ix)
                for (int jy = 0; jy < p; ++jy) {
                    int x1 = (int)cround(rx_[r] + ix * len);
                    int x2 = (int)cround(rx_[r] + ix * len + len);
                    int y1 = (int)cround(ry_[r] + jy * len);
                    int y2 = (int)cround(ry_[r] + jy * len + len);
                    out.b[nb] = Box{y1, y2, x1, x2};
                    ++nb;
                }
        }
    }
    return out;
}
constexpr BoxArr BOXES = make_boxes();

// distinct x-interval dedup
struct Meta { int nxi; int xlo[32]; int xhi[32]; int xid[NR]; };
constexpr Meta make_meta() {
    Meta m{};
    m.nxi = 0;
    for (int r = 0; r < NR; ++r) {
        int lo = BOXES.b[r].x1, hi = BOXES.b[r].x2, id = -1;
        for (int i = 0; i < m.nxi; ++i) if (m.xlo[i] == lo && m.xhi[i] == hi) { id = i; break; }
        if (id < 0) { id = m.nxi; m.xlo[id] = lo; m.xhi[id] = hi; m.nxi++; }
        m.xid[r] = id;
    }
    return m;
}
constexpr Meta MT = make_meta();
constexpr int NXI = MT.nxi;
static_assert(NXI == 14, "expected 14 distinct x-intervals");

// per-h box lists (boxes whose [y1,y2) contains h) -- register y-fold
struct HRows { int cnt[Hh]; int idx[Hh][40]; };
constexpr HRows make_hb() {
    HRows hb{};
    for (int h = 0; h < Hh; ++h) {
        hb.cnt[h] = 0;
        for (int r = 0; r < NR; ++r)
            if (BOXES.b[r].y1 <= h && h < BOXES.b[r].y2) {
                hb.idx[h][hb.cnt[h]] = r;
                hb.cnt[h]++;
            }
    }
    return hb;
}
constexpr HRows HB = make_hb();
constexpr int hb_max() { int m = 0; for (int h = 0; h < Hh; ++h) m = HB.cnt[h] > m ? HB.cnt[h] : m; return m; }
static_assert(hb_max() <= 40, "HB idx array too small");

__device__ __forceinline__ ushort f2bf(float f) {  // RNE float->bf16 (finite; -inf ok)
    union { float f; unsigned u; } v; v.f = f;
    unsigned r = v.u + 0x7FFFu + ((v.u >> 16) & 1u);
    return (ushort)(r >> 16);
}
__device__ __forceinline__ float bf2f(ushort u) {
    union { unsigned u; float f; } v; v.u = ((unsigned)u) << 16;
    return v.f;
}

// swizzled index into m[*][512]: 16B slots XOR'd by row&7 (matches GEMM read)
__device__ __forceinline__ int midx(int r, int c) {
    return r * Cc + (((c >> 3) ^ (r & 7)) << 3) + (c & 7);
}

// ---------------- kernel 0: W fp32 -> bf16 ----------------
__global__ __launch_bounds__(256) void k_convw(const float* __restrict__ w,
                                               ushort* __restrict__ o) {
    int i = (blockIdx.x * 256 + threadIdx.x) * 4;
    float4 f = *(const float4*)&w[i];
    ushort4 u;
    u.x = f2bf(f.x); u.y = f2bf(f.y); u.z = f2bf(f.z); u.w = f2bf(f.w);
    *(ushort4*)&o[i] = u;
}

// ---------------- kernel 1: barrier-free pooling waves -----------------------
// grid 4096 = 512 b x 8 channel-slices; 64 threads = 1 wave; NO LDS, NO barriers.
// Each wave = independent R7-style register pooling chain (thread = channel,
// row double-buffer, live-range retirement). Writes bf16 m to workspace in the
// pre-swizzled layout (bit-identical values/positions to the fused m_s).
__global__ __launch_bounds__(64) void k_pool(const float* __restrict__ x,
                                             ushort* __restrict__ mg) {
    const int bid = blockIdx.x;
    const int b = bid >> 3, s = bid & 7;
    const int c = s * 64 + (int)threadIdx.x;          // channel owned by this thread

    const float* xc = x + (size_t)b * (Hh * Ww * Cc) + c;
    ushort* mb = mg + (size_t)b * (PadR * Cc);

    float acc70[NR];                                  // live-range managed
    float rowbuf[2][Ww];
    #pragma unroll
    for (int w = 0; w < Ww; ++w) rowbuf[0][w] = xc[w * Cc];

    #pragma unroll
    for (int h = 0; h < Hh; ++h) {
        if (h + 1 < Hh) {                             // prefetch next row
            #pragma unroll
            for (int w = 0; w < Ww; ++w)
                rowbuf[(h + 1) & 1][w] = xc[((h + 1) * Ww + w) * Cc];
        }
        float rmx[NXI];
        #pragma unroll
        for (int xi = 0; xi < NXI; ++xi) {
            float mm = rowbuf[h & 1][MT.xlo[xi]];
            #pragma unroll
            for (int w = MT.xlo[xi] + 1; w < MT.xhi[xi]; ++w)
                mm = fmaxf(mm, rowbuf[h & 1][w]);
            rmx[xi] = mm;
        }
        #pragma unroll
        for (int bi = 0; bi < HB.cnt[h]; ++bi) {
            const int r = HB.idx[h][bi];              // compile-time
            const float v = rmx[MT.xid[r]];
            acc70[r] = (BOXES.b[r].y1 == h) ? v : fmaxf(acc70[r], v);
            if (BOXES.b[r].y2 == h + 1)               // retire: quantize once
                mb[midx(r, c)] = f2bf(acc70[r]);
        }
    }
}

// ---------------- kernel 2: stage m -> SS -> GEMM -> fused epilogue ----------
__global__ __launch_bounds__(512) void k_gemm(const ushort* __restrict__ mg,
                                              const ushort* __restrict__ wbf,
                                              const float* __restrict__ bias,
                                              float* __restrict__ out) {
    __shared__ __align__(16) ushort m_s[MROWS * Cc];         // 72 KB, swizzled layout
    __shared__ float ss_s[PadR];

    struct EScratch {                                        // aliases m_s post-GEMM
        float rowss[PadR][8];
        float rns[PadR];
        float y_s[Cc];
        float red2[8];
    };
    EScratch* sc = (EScratch*)m_s;

    const int b = blockIdx.x;
    const int tid = threadIdx.x;
    const int lane = tid & 63;
    const int wv = tid >> 6;                // 0..7
    const int l15 = lane & 15, lhi = lane >> 4;

    // stage m rows 0..69 (4480 x 16B) from workspace; zero rows 70,71; ss tail
    {
        const bf16x8* src = (const bf16x8*)(mg + (size_t)b * (PadR * Cc));
        bf16x8* dst = (bf16x8*)m_s;
        #pragma unroll
        for (int i = 0; i < 8; ++i) dst[tid + i * 512] = src[tid + i * 512];
        if (tid < 384) dst[tid + 4096] = src[tid + 4096];
        uint* z = (uint*)&m_s[70 * Cc];
        z[tid] = 0;
        if (tid >= 70 && tid < PadR) ss_s[tid] = 0.f;
    }
    __syncthreads();                         // m_s complete

    // ---- SS from m_s (same read/accumulate order as previous rounds) ----
    #pragma unroll
    for (int i = 0; i < 9; ++i) {
        const int rr = wv * 9 + i;
        if (rr < NR) {
            float s = 0.f;
            #pragma unroll
            for (int cg = 0; cg < 4; ++cg) {
                ushort2 t2 = *(const ushort2*)&m_s[midx(rr, cg * 128 + 2 * lane)];
                float m0 = bf2f(t2.x), m1 = bf2f(t2.y);
                s += m0 * m0 + m1 * m1;
            }
            s += __shfl_xor(s, 1);  s += __shfl_xor(s, 2);  s += __shfl_xor(s, 4);
            s += __shfl_xor(s, 8);  s += __shfl_xor(s, 16); s += __shfl_xor(s, 32);
            if (lane == 0) ss_s[rr] = s;
        }
    }
    __syncthreads();                         // ss_s ready

    // ---- GEMM: t[80][512] = m * W^T, A resident in m_s, no barriers ----
    f32x4 acc[5][4];
    #pragma unroll
    for (int mi = 0; mi < 5; ++mi)
        #pragma unroll
        for (int ni = 0; ni < 4; ++ni) acc[mi][ni] = (f32x4){0.f, 0.f, 0.f, 0.f};

    auto loadB = [&](bf16x8 (&bf)[4][2], int k0) {
        #pragma unroll
        for (int ni = 0; ni < 4; ++ni)
            #pragma unroll
            for (int kh = 0; kh < 2; ++kh)
                bf[ni][kh] = *(const bf16x8*)(wbf + (size_t)(wv * 64 + ni * 16 + l15) * Cc
                                              + k0 + kh * 32 + lhi * 8);
    };

    bf16x8 bfc[4][2], bfn[4][2];
    loadB(bfc, 0);
    #pragma unroll
    for (int ks = 0; ks < 8; ++ks) {
        if (ks < 7) loadB(bfn, (ks + 1) * 64);
        #pragma unroll
        for (int kh = 0; kh < 2; ++kh) {
            bf16x8 af[5];
            #pragma unroll
            for (int mi = 0; mi < 5; ++mi) {
                int row_ = mi * 16 + l15;
                // rows 72..79 don't exist in LDS: remap to zero rows 70/71
                int rc = (mi < 4) ? row_
                                  : ((row_ < MROWS) ? row_ : (70 | (row_ & 1)));
                int slot = (ks * 8 + kh * 4 + lhi) ^ (rc & 7);
                af[mi] = *(const bf16x8*)&m_s[rc * Cc + slot * 8];
            }
            #pragma unroll
            for (int mi = 0; mi < 5; ++mi)
                #pragma unroll
                for (int ni = 0; ni < 4; ++ni)
                    acc[mi][ni] = __builtin_amdgcn_mfma_f32_16x16x32_bf16(
                        af[mi], bfc[ni][kh], acc[mi][ni], 0, 0, 0);
        }
        #pragma unroll
        for (int ni = 0; ni < 4; ++ni)
            #pragma unroll
            for (int kh = 0; kh < 2; ++kh) bfc[ni][kh] = bfn[ni][kh];
    }
    __syncthreads();                          // m_s reads done; epilogue may alias

    // ---- fused epilogue: deferred A-norm + bias, row-norm, sum, final norm ----
    float bia[4];
    #pragma unroll
    for (int ni = 0; ni < 4; ++ni) bia[ni] = bias[wv * 64 + ni * 16 + l15];
    float rm[5][4];
    #pragma unroll
    for (int mi = 0; mi < 5; ++mi)
        #pragma unroll
        for (int j = 0; j < 4; ++j)
            rm[mi][j] = 1.f / fmaxf(sqrtf(ss_s[mi * 16 + lhi * 4 + j]), 1e-12f);
    #pragma unroll
    for (int mi = 0; mi < 5; ++mi)
        #pragma unroll
        for (int ni = 0; ni < 4; ++ni)
            #pragma unroll
            for (int j = 0; j < 4; ++j)
                acc[mi][ni][j] = fmaf(acc[mi][ni][j], rm[mi][j], bia[ni]);

    #pragma unroll
    for (int mi = 0; mi < 5; ++mi)
        #pragma unroll
        for (int j = 0; j < 4; ++j) {
            float s = 0.f;
            #pragma unroll
            for (int ni = 0; ni < 4; ++ni) s += acc[mi][ni][j] * acc[mi][ni][j];
            s += __shfl_xor(s, 1); s += __shfl_xor(s, 2);
            s += __shfl_xor(s, 4); s += __shfl_xor(s, 8);
            if (l15 == 0) sc->rowss[mi * 16 + lhi * 4 + j][wv] = s;
        }
    __syncthreads();
    if (tid < PadR) {
        float s = 0.f;
        #pragma unroll
        for (int w8 = 0; w8 < 8; ++w8) s += sc->rowss[tid][w8];
        sc->rns[tid] = 1.f / fmaxf(sqrtf(s), 1e-12f);
    }
    __syncthreads();

    float ys[4] = {0.f, 0.f, 0.f, 0.f};
    #pragma unroll
    for (int mi = 0; mi < 5; ++mi)
        #pragma unroll
        for (int j = 0; j < 4; ++j) {
            int row_ = mi * 16 + lhi * 4 + j;
            float w = (row_ < NR) ? sc->rns[row_] : 0.f;   // skip pad rows
            #pragma unroll
            for (int ni = 0; ni < 4; ++ni) ys[ni] = fmaf(acc[mi][ni][j], w, ys[ni]);
        }
    #pragma unroll
    for (int ni = 0; ni < 4; ++ni) {
        ys[ni] += __shfl_xor(ys[ni], 16);
        ys[ni] += __shfl_xor(ys[ni], 32);
    }
    if (lane < 16)
        #pragma unroll
        for (int ni = 0; ni < 4; ++ni) sc->y_s[wv * 64 + ni * 16 + lane] = ys[ni];
    __syncthreads();

    float yv = sc->y_s[tid];
    float s2 = yv * yv;
    s2 += __shfl_xor(s2, 1);  s2 += __shfl_xor(s2, 2);  s2 += __shfl_xor(s2, 4);
    s2 += __shfl_xor(s2, 8);  s2 += __shfl_xor(s2, 16); s2 += __shfl_xor(s2, 32);
    if (lane == 0) sc->red2[wv] = s2;
    __syncthreads();
    float tot = 0.f;
    #pragma unroll
    for (int w8 = 0; w8 < 8; ++w8) tot += sc->red2[w8];
    out[(size_t)b * Cc + tid] = yv / fmaxf(sqrtf(tot), 1e-12f);
}

// ---------------- fallback: round-7 fused kernel (known-good, 86 us) ---------
__global__ __launch_bounds__(512) void k_fused_fb(const float* __restrict__ x,
                                                  const ushort* __restrict__ wbf,
                                                  const float* __restrict__ bias,
                                                  float* __restrict__ out) {
    __shared__ __align__(16) ushort m_s[MROWS * Cc];
    __shared__ float ss_s[PadR];
    struct EScratch {
        float rowss[PadR][8];
        float rns[PadR];
        float y_s[Cc];
        float red2[8];
    };
    EScratch* sc = (EScratch*)m_s;

    const int b = blockIdx.x;
    const int tid = threadIdx.x;
    const int lane = tid & 63;
    const int wv = tid >> 6;
    const int l15 = lane & 15, lhi = lane >> 4;

    {
        uint* z = (uint*)&m_s[70 * Cc];
        z[tid] = 0;
        if (tid >= 70 && tid < PadR) ss_s[tid] = 0.f;
    }

    float acc70[NR];
    const float* xc = x + (size_t)b * (Hh * Ww * Cc) + tid;

    float rowbuf[2][Ww];
    #pragma unroll
    for (int w = 0; w < Ww; ++w) rowbuf[0][w] = xc[w * Cc];

    #pragma unroll
    for (int h = 0; h < Hh; ++h) {
        if (h + 1 < Hh) {
            #pragma unroll
            for (int w = 0; w < Ww; ++w)
                rowbuf[(h + 1) & 1][w] = xc[((h + 1) * Ww + w) * Cc];
        }
        float rmx[NXI];
        #pragma unroll
        for (int xi = 0; xi < NXI; ++xi) {
            float mm = rowbuf[h & 1][MT.xlo[xi]];
            #pragma unroll
            for (int w = MT.xlo[xi] + 1; w < MT.xhi[xi]; ++w)
                mm = fmaxf(mm, rowbuf[h & 1][w]);
            rmx[xi] = mm;
        }
        #pragma unroll
        for (int bi = 0; bi < HB.cnt[h]; ++bi) {
            const int r = HB.idx[h][bi];
            const float v = rmx[MT.xid[r]];
            acc70[r] = (BOXES.b[r].y1 == h) ? v : fmaxf(acc70[r], v);
            if (BOXES.b[r].y2 == h + 1)
                m_s[midx(r, tid)] = f2bf(acc70[r]);
        }
    }
    __syncthreads();

    #pragma unroll
    for (int i = 0; i < 9; ++i) {
        const int rr = wv * 9 + i;
        if (rr < NR) {
            float s = 0.f;
            #pragma unroll
            for (int cg = 0; cg < 4; ++cg) {
                ushort2 t2 = *(const ushort2*)&m_s[midx(rr, cg * 128 + 2 * lane)];
                float m0 = bf2f(t2.x), m1 = bf2f(t2.y);
                s += m0 * m0 + m1 * m1;
            }
            s += __shfl_xor(s, 1);  s += __shfl_xor(s, 2);  s += __shfl_xor(s, 4);
            s += __shfl_xor(s, 8);  s += __shfl_xor(s, 16); s += __shfl_xor(s, 32);
            if (lane == 0) ss_s[rr] = s;
        }
    }
    __syncthreads();

    f32x4 acc[5][4];
    #pragma unroll
    for (int mi = 0; mi < 5; ++mi)
        #pragma unroll
        for (int ni = 0; ni < 4; ++ni) acc[mi][ni] = (f32x4){0.f, 0.f, 0.f, 0.f};

    auto loadB = [&](bf16x8 (&bf)[4][2], int k0) {
        #pragma unroll
        for (int ni = 0; ni < 4; ++ni)
            #pragma unroll
            for (int kh = 0; kh < 2; ++kh)
                bf[ni][kh] = *(const bf16x8*)(wbf + (size_t)(wv * 64 + ni * 16 + l15) * Cc
                                              + k0 + kh * 32 + lhi * 8);
    };

    bf16x8 bfc[4][2], bfn[4][2];
    loadB(bfc, 0);
    #pragma unroll
    for (int ks = 0; ks < 8; ++ks) {
        if (ks < 7) loadB(bfn, (ks + 1) * 64);
        #pragma unroll
        for (int kh = 0; kh < 2; ++kh) {
            bf16x8 af[5];
            #pragma unroll
            for (int mi = 0; mi < 5; ++mi) {
                int row_ = mi * 16 + l15;
                int rc = (mi < 4) ? row_
                                  : ((row_ < MROWS) ? row_ : (70 | (row_ & 1)));
                int slot = (ks * 8 + kh * 4 + lhi) ^ (rc & 7);
                af[mi] = *(const bf16x8*)&m_s[rc * Cc + slot * 8];
            }
            #pragma unroll
            for (int mi = 0; mi < 5; ++mi)
                #pragma unroll
                for (int ni = 0; ni < 4; ++ni)
                    acc[mi][ni] = __builtin_amdgcn_mfma_f32_16x16x32_bf16(
                        af[mi], bfc[ni][kh], acc[mi][ni], 0, 0, 0);
        }
        #pragma unroll
        for (int ni = 0; ni < 4; ++ni)
            #pragma unroll
            for (int kh = 0; kh < 2; ++kh) bfc[ni][kh] = bfn[ni][kh];
    }
    __syncthreads();

    float bia[4];
    #pragma unroll
    for (int ni = 0; ni < 4; ++ni) bia[ni] = bias[wv * 64 + ni * 16 + l15];
    float rm[5][4];
    #pragma unroll
    for (int mi = 0; mi < 5; ++mi)
        #pragma unroll
        for (int j = 0; j < 4; ++j)
            rm[mi][j] = 1.f / fmaxf(sqrtf(ss_s[mi * 16 + lhi * 4 + j]), 1e-12f);
    #pragma unroll
    for (int mi = 0; mi < 5; ++mi)
        #pragma unroll
        for (int ni = 0; ni < 4; ++ni)
            #pragma unroll
            for (int j = 0; j < 4; ++j)
                acc[mi][ni][j] = fmaf(acc[mi][ni][j], rm[mi][j], bia[ni]);

    #pragma unroll
    for (int mi = 0; mi < 5; ++mi)
        #pragma unroll
        for (int j = 0; j < 4; ++j) {
            float s = 0.f;
            #pragma unroll
            for (int ni = 0; ni < 4; ++ni) s += acc[mi][ni][j] * acc[mi][ni][j];
            s += __shfl_xor(s, 1); s += __shfl_xor(s, 2);
            s += __shfl_xor(s, 4); s += __shfl_xor(s, 8);
            if (l15 == 0) sc->rowss[mi * 16 + lhi * 4 + j][wv] = s;
        }
    __syncthreads();
    if (tid < PadR) {
        float s = 0.f;
        #pragma unroll
        for (int w8 = 0; w8 < 8; ++w8) s += sc->rowss[tid][w8];
        sc->rns[tid] = 1.f / fmaxf(sqrtf(s), 1e-12f);
    }
    __syncthreads();

    float ys[4] = {0.f, 0.f, 0.f, 0.f};
    #pragma unroll
    for (int mi = 0; mi < 5; ++mi)
        #pragma unroll
        for (int j = 0; j < 4; ++j) {
            int row_ = mi * 16 + lhi * 4 + j;
            float w = (row_ < NR) ? sc->rns[row_] : 0.f;
            #pragma unroll
            for (int ni = 0; ni < 4; ++ni) ys[ni] = fmaf(acc[mi][ni][j], w, ys[ni]);
        }
    #pragma unroll
    for (int ni = 0; ni < 4; ++ni) {
        ys[ni] += __shfl_xor(ys[ni], 16);
        ys[ni] += __shfl_xor(ys[ni], 32);
    }
    if (lane < 16)
        #pragma unroll
        for (int ni = 0; ni < 4; ++ni) sc->y_s[wv * 64 + ni * 16 + lane] = ys[ni];
    __syncthreads();

    float yv = sc->y_s[tid];
    float s2 = yv * yv;
    s2 += __shfl_xor(s2, 1);  s2 += __shfl_xor(s2, 2);  s2 += __shfl_xor(s2, 4);
    s2 += __shfl_xor(s2, 8);  s2 += __shfl_xor(s2, 16); s2 += __shfl_xor(s2, 32);
    if (lane == 0) sc->red2[wv] = s2;
    __syncthreads();
    float tot = 0.f;
    #pragma unroll
    for (int w8 = 0; w8 < 8; ++w8) tot += sc->red2[w8];
    out[(size_t)b * Cc + tid] = yv / fmaxf(sqrtf(tot), 1e-12f);
}

// ---------------- launch ----------------
extern "C" void kernel_launch(void* const* d_in, const int* in_sizes, int n_in,
                              void* d_out, int out_size, void* d_ws, size_t ws_size,
                              hipStream_t stream) {
    const float* x  = (const float*)d_in[0];
    const float* pw = (const float*)d_in[1];
    const float* pb = (const float*)d_in[2];
    float* out = (float*)d_out;

    // workspace layout: wbf (0.5 MB) | mg (41.9 MB)
    constexpr size_t OFF_MG = 524288;
    constexpr size_t NEEDED = OFF_MG + (size_t)Bb * PadR * Cc * 2;   // ~42.5 MB

    ushort* wbf = (ushort*)d_ws;
    k_convw<<<dim3(256), dim3(256), 0, stream>>>(pw, wbf);

    if (ws_size >= NEEDED) {
        ushort* mg = (ushort*)((char*)d_ws + OFF_MG);
        k_pool<<<dim3(Bb * 8), dim3(64), 0, stream>>>(x, mg);
        k_gemm<<<dim3(Bb), dim3(512), 0, stream>>>(mg, wbf, pb, out);
    } else {
        k_fused_fb<<<dim3(Bb), dim3(512), 0, stream>>>(x, wbf, pb, out);
    }
}

// Round 9
// 84.475 us; speedup vs baseline: 1.1890x; 1.1890x over previous
//
#include <hip/hip_runtime.h>
#include <type_traits>

typedef short bf16x8 __attribute__((ext_vector_type(8)));
typedef float f32x4 __attribute__((ext_vector_type(4)));

// ---------------- problem constants ----------------
constexpr int Hh = 14, Ww = 14, Cc = 512, Bb = 512, NR = 70, PadR = 80;
constexpr int MROWS = 72;   // LDS rows for m: 70 data + 2 zero rows (72..79 remapped)

// ---------------- constexpr replication of _crop_boxes ----------------
struct Box { int y1, y2, x1, x2; };

constexpr double cfloor(double v) { return (double)(long long)v; }  // v >= 0 only
constexpr double cround(double v) {  // np.round: half-to-even
    double f = cfloor(v);
    double fr = v - f;
    if (fr > 0.5) return f + 1.0;
    if (fr < 0.5) return f;
    return (((long long)f) & 1LL) ? f + 1.0 : f;
}

struct BoxArr { Box b[NR]; };

constexpr BoxArr make_boxes() {
    BoxArr out{};
    double rx_[14] = {}, ry_[14] = {}, wl_[14] = {};
    int nr = 0;
    for (int l = 1; l <= 3; ++l) {
        double wl  = cfloor(2.0 * 14.0 / (double)(l + 1));
        double wl2 = cfloor(wl / 2.0 - 1.0);
        double bb  = (l > 1) ? (14.0 - wl) / (double)(l - 1) : 0.0;
        double cen[3] = {};
        for (int k = 0; k < l; ++k) cen[k] = cfloor(wl2 + (double)k * bb) - wl2;
        for (int i = 0; i < l; ++i)
            for (int j = 0; j < l; ++j) { rx_[nr] = cen[j]; ry_[nr] = cen[i]; wl_[nr] = wl; ++nr; }
    }
    int nb = 0;
    for (int r = 0; r < nr; ++r) {
        for (int p = 1; p <= 2; ++p) {
            double len = wl_[r] / (double)p;
            for (int ix = 0; ix < p; ++ix)
                for (int jy = 0; jy < p; ++jy) {
                    int x1 = (int)cround(rx_[r] + ix * len);
                    int x2 = (int)cround(rx_[r] + ix * len + len);
                    int y1 = (int)cround(ry_[r] + jy * len);
                    int y2 = (int)cround(ry_[r] + jy * len + len);
                    out.b[nb] = Box{y1, y2, x1, x2};
                    ++nb;
                }
        }
    }
    return out;
}
constexpr BoxArr BOXES = make_boxes();

// distinct x-interval dedup
struct Meta { int nxi; int xlo[32]; int xhi[32]; int xid[NR]; };
constexpr Meta make_meta() {
    Meta m{};
    m.nxi = 0;
    for (int r = 0; r < NR; ++r) {
        int lo = BOXES.b[r].x1, hi = BOXES.b[r].x2, id = -1;
        for (int i = 0; i < m.nxi; ++i) if (m.xlo[i] == lo && m.xhi[i] == hi) { id = i; break; }
        if (id < 0) { id = m.nxi; m.xlo[id] = lo; m.xhi[id] = hi; m.nxi++; }
        m.xid[r] = id;
    }
    return m;
}
constexpr Meta MT = make_meta();
constexpr int NXI = MT.nxi;
static_assert(NXI == 14, "expected 14 distinct x-intervals");

// per-h box lists (boxes whose [y1,y2) contains h) -- register y-fold
struct HRows { int cnt[Hh]; int idx[Hh][40]; };
constexpr HRows make_hb() {
    HRows hb{};
    for (int h = 0; h < Hh; ++h) {
        hb.cnt[h] = 0;
        for (int r = 0; r < NR; ++r)
            if (BOXES.b[r].y1 <= h && h < BOXES.b[r].y2) {
                hb.idx[h][hb.cnt[h]] = r;
                hb.cnt[h]++;
            }
    }
    return hb;
}
constexpr HRows HB = make_hb();
constexpr int hb_max() { int m = 0; for (int h = 0; h < Hh; ++h) m = HB.cnt[h] > m ? HB.cnt[h] : m; return m; }
static_assert(hb_max() <= 40, "HB idx array too small");

__device__ __forceinline__ ushort f2bf(float f) {  // RNE float->bf16 (finite; -inf ok)
    union { float f; unsigned u; } v; v.f = f;
    unsigned r = v.u + 0x7FFFu + ((v.u >> 16) & 1u);
    return (ushort)(r >> 16);
}
__device__ __forceinline__ float bf2f(ushort u) {
    union { unsigned u; float f; } v; v.u = ((unsigned)u) << 16;
    return v.f;
}

// swizzled index into m_s[*][512]: 16B slots XOR'd by row&7 (matches GEMM read)
__device__ __forceinline__ int midx(int r, int c) {
    return r * Cc + (((c >> 3) ^ (r & 7)) << 3) + (c & 7);
}

// async global -> LDS, 16 B per lane (fire-and-forget, counted by vmcnt)
__device__ __forceinline__ void gload_lds16(const void* g, void* l) {
    __builtin_amdgcn_global_load_lds(
        (const __attribute__((address_space(1))) unsigned int*)g,
        (__attribute__((address_space(3))) unsigned int*)l,
        16, 0, 0);
}

// ---------------- kernel 0: W fp32 -> bf16 ----------------
__global__ __launch_bounds__(256) void k_convw(const float* __restrict__ w,
                                               ushort* __restrict__ o) {
    int i = (blockIdx.x * 256 + threadIdx.x) * 4;
    float4 f = *(const float4*)&w[i];
    ushort4 u;
    u.x = f2bf(f.x); u.y = f2bf(f.y); u.z = f2bf(f.z); u.w = f2bf(f.w);
    *(ushort4*)&o[i] = u;
}

// ---------------- fused: direct-to-LDS streamed pooling -> GEMM ------------------
// Per row-step h: issue row h+1 (28 KB) via global_load_lds width-16 bursts (deep
// VMEM queue, no VGPR round-trip), fold row h from LDS (14 conflict-free
// ds_read_b32/thread) into register accumulators (live-range birth, R6/R7
// numerics). __syncthreads per step = the depth-1 pipeline drain. xbuf[2] (56 KB)
// unions with m_s (72 KB). SS + GEMM + epilogue verbatim from round 7.
__global__ __launch_bounds__(512, 4) void k_fused(const float* __restrict__ x,
                                                  const ushort* __restrict__ wbf,
                                                  const float* __restrict__ bias,
                                                  float* __restrict__ out) {
    __shared__ __align__(16) union UU {
        float xbuf[2][Ww * Cc];                      // 2 x 28 KB row buffers
        ushort m_s[MROWS * Cc];                      // 72 KB (union = 72 KB)
    } u;
    __shared__ float ss_s[PadR];

    struct EScratch {                                // aliases m_s post-GEMM
        float rowss[PadR][8];
        float rns[PadR];
        float y_s[Cc];
        float red2[8];
    };
    EScratch* sc = (EScratch*)u.m_s;

    const int b = blockIdx.x;
    const int tid = threadIdx.x;
    const int lane = tid & 63;
    const int wv = tid >> 6;                // 0..7
    const int l15 = lane & 15, lhi = lane >> 4;

    if (tid >= 70 && tid < PadR) ss_s[tid] = 0.f;

    const char* xb = (const char*)(x + (size_t)b * (Hh * Ww * Cc));

    // issue one image row (28672 B) into xbuf[h&1]: waves 0..6, 4 x 16B each
    auto issueRow = [&](int h) {
        if (tid < 448) {
            const char* src = xb + (size_t)h * (Ww * Cc * 4);
            char* dst = (char*)u.xbuf[h & 1];
            #pragma unroll
            for (int i = 0; i < 4; ++i) {
                const int off = i * 7168 + tid * 16;
                gload_lds16(src + off, dst + off);
            }
        }
    };

    float acc70[NR];                         // live-range managed (birth at y1)

    issueRow(0);
    __syncthreads();                         // row 0 resident (vmcnt(0) drain)

    #pragma unroll
    for (int h = 0; h < Hh; ++h) {
        if (h + 1 < Hh) issueRow(h + 1);     // stream next row under this fold
        // fold row h from LDS: thread = channel tid
        float row[Ww];
        #pragma unroll
        for (int w = 0; w < Ww; ++w) row[w] = u.xbuf[h & 1][w * Cc + tid];
        float rmx[NXI];
        #pragma unroll
        for (int xi = 0; xi < NXI; ++xi) {
            float mm = row[MT.xlo[xi]];
            #pragma unroll
            for (int w = MT.xlo[xi] + 1; w < MT.xhi[xi]; ++w) mm = fmaxf(mm, row[w]);
            rmx[xi] = mm;
        }
        #pragma unroll
        for (int bi = 0; bi < HB.cnt[h]; ++bi) {
            const int r = HB.idx[h][bi];                     // compile-time
            const float v = rmx[MT.xid[r]];
            acc70[r] = (BOXES.b[r].y1 == h) ? v : fmaxf(acc70[r], v);
        }
        __syncthreads();                     // next row's loads drained; buf reusable
    }

    // ---- handoff: m_s aliases xbuf (all reads done); quantize once ----
    {
        uint* z = (uint*)&u.m_s[70 * Cc];
        z[tid] = 0;                          // zero rows 70,71 (512 uints)
        #pragma unroll
        for (int r = 0; r < NR; ++r) u.m_s[midx(r, tid)] = f2bf(acc70[r]);
    }
    __syncthreads();                         // m_s complete

    // ---- SS from m_s (same read/accumulate order as previous rounds) ----
    #pragma unroll
    for (int i = 0; i < 9; ++i) {
        const int rr = wv * 9 + i;
        if (rr < NR) {
            float s = 0.f;
            #pragma unroll
            for (int cg = 0; cg < 4; ++cg) {
                ushort2 t2 = *(const ushort2*)&u.m_s[midx(rr, cg * 128 + 2 * lane)];
                float m0 = bf2f(t2.x), m1 = bf2f(t2.y);
                s += m0 * m0 + m1 * m1;
            }
            s += __shfl_xor(s, 1);  s += __shfl_xor(s, 2);  s += __shfl_xor(s, 4);
            s += __shfl_xor(s, 8);  s += __shfl_xor(s, 16); s += __shfl_xor(s, 32);
            if (lane == 0) ss_s[rr] = s;
        }
    }
    __syncthreads();                         // ss_s ready

    // ---- GEMM: t[80][512] = m * W^T, A resident in m_s, no barriers ----
    f32x4 acc[5][4];
    #pragma unroll
    for (int mi = 0; mi < 5; ++mi)
        #pragma unroll
        for (int ni = 0; ni < 4; ++ni) acc[mi][ni] = (f32x4){0.f, 0.f, 0.f, 0.f};

    auto loadB = [&](bf16x8 (&bf)[4][2], int k0) {
        #pragma unroll
        for (int ni = 0; ni < 4; ++ni)
            #pragma unroll
            for (int kh = 0; kh < 2; ++kh)
                bf[ni][kh] = *(const bf16x8*)(wbf + (size_t)(wv * 64 + ni * 16 + l15) * Cc
                                              + k0 + kh * 32 + lhi * 8);
    };

    bf16x8 bfc[4][2], bfn[4][2];
    loadB(bfc, 0);
    #pragma unroll
    for (int ks = 0; ks < 8; ++ks) {
        if (ks < 7) loadB(bfn, (ks + 1) * 64);
        #pragma unroll
        for (int kh = 0; kh < 2; ++kh) {
            bf16x8 af[5];
            #pragma unroll
            for (int mi = 0; mi < 5; ++mi) {
                int row_ = mi * 16 + l15;
                // rows 72..79 don't exist in LDS: remap to zero rows 70/71
                int rc = (mi < 4) ? row_
                                  : ((row_ < MROWS) ? row_ : (70 | (row_ & 1)));
                int slot = (ks * 8 + kh * 4 + lhi) ^ (rc & 7);
                af[mi] = *(const bf16x8*)&u.m_s[rc * Cc + slot * 8];
            }
            #pragma unroll
            for (int mi = 0; mi < 5; ++mi)
                #pragma unroll
                for (int ni = 0; ni < 4; ++ni)
                    acc[mi][ni] = __builtin_amdgcn_mfma_f32_16x16x32_bf16(
                        af[mi], bfc[ni][kh], acc[mi][ni], 0, 0, 0);
        }
        #pragma unroll
        for (int ni = 0; ni < 4; ++ni)
            #pragma unroll
            for (int kh = 0; kh < 2; ++kh) bfc[ni][kh] = bfn[ni][kh];
    }
    __syncthreads();                          // m_s reads done; epilogue may alias

    // ---- fused epilogue: deferred A-norm + bias, row-norm, sum, final norm ----
    float bia[4];
    #pragma unroll
    for (int ni = 0; ni < 4; ++ni) bia[ni] = bias[wv * 64 + ni * 16 + l15];
    float rm[5][4];
    #pragma unroll
    for (int mi = 0; mi < 5; ++mi)
        #pragma unroll
        for (int j = 0; j < 4; ++j)
            rm[mi][j] = 1.f / fmaxf(sqrtf(ss_s[mi * 16 + lhi * 4 + j]), 1e-12f);
    #pragma unroll
    for (int mi = 0; mi < 5; ++mi)
        #pragma unroll
        for (int ni = 0; ni < 4; ++ni)
            #pragma unroll
            for (int j = 0; j < 4; ++j)
                acc[mi][ni][j] = fmaf(acc[mi][ni][j], rm[mi][j], bia[ni]);

    #pragma unroll
    for (int mi = 0; mi < 5; ++mi)
        #pragma unroll
        for (int j = 0; j < 4; ++j) {
            float s = 0.f;
            #pragma unroll
            for (int ni = 0; ni < 4; ++ni) s += acc[mi][ni][j] * acc[mi][ni][j];
            s += __shfl_xor(s, 1); s += __shfl_xor(s, 2);
            s += __shfl_xor(s, 4); s += __shfl_xor(s, 8);
            if (l15 == 0) sc->rowss[mi * 16 + lhi * 4 + j][wv] = s;
        }
    __syncthreads();
    if (tid < PadR) {
        float s = 0.f;
        #pragma unroll
        for (int w8 = 0; w8 < 8; ++w8) s += sc->rowss[tid][w8];
        sc->rns[tid] = 1.f / fmaxf(sqrtf(s), 1e-12f);
    }
    __syncthreads();

    float ys[4] = {0.f, 0.f, 0.f, 0.f};
    #pragma unroll
    for (int mi = 0; mi < 5; ++mi)
        #pragma unroll
        for (int j = 0; j < 4; ++j) {
            int row_ = mi * 16 + lhi * 4 + j;
            float w = (row_ < NR) ? sc->rns[row_] : 0.f;   // skip pad rows
            #pragma unroll
            for (int ni = 0; ni < 4; ++ni) ys[ni] = fmaf(acc[mi][ni][j], w, ys[ni]);
        }
    #pragma unroll
    for (int ni = 0; ni < 4; ++ni) {
        ys[ni] += __shfl_xor(ys[ni], 16);
        ys[ni] += __shfl_xor(ys[ni], 32);
    }
    if (lane < 16)
        #pragma unroll
        for (int ni = 0; ni < 4; ++ni) sc->y_s[wv * 64 + ni * 16 + lane] = ys[ni];
    __syncthreads();

    float yv = sc->y_s[tid];
    float s2 = yv * yv;
    s2 += __shfl_xor(s2, 1);  s2 += __shfl_xor(s2, 2);  s2 += __shfl_xor(s2, 4);
    s2 += __shfl_xor(s2, 8);  s2 += __shfl_xor(s2, 16); s2 += __shfl_xor(s2, 32);
    if (lane == 0) sc->red2[wv] = s2;
    __syncthreads();
    float tot = 0.f;
    #pragma unroll
    for (int w8 = 0; w8 < 8; ++w8) tot += sc->red2[w8];
    out[(size_t)b * Cc + tid] = yv / fmaxf(sqrtf(tot), 1e-12f);
}

// ---------------- launch ----------------
extern "C" void kernel_launch(void* const* d_in, const int* in_sizes, int n_in,
                              void* d_out, int out_size, void* d_ws, size_t ws_size,
                              hipStream_t stream) {
    const float* x  = (const float*)d_in[0];
    const float* pw = (const float*)d_in[1];
    const float* pb = (const float*)d_in[2];
    float* out = (float*)d_out;

    ushort* wbf = (ushort*)d_ws;                          // 512x512 bf16 = 0.5 MB

    k_convw<<<dim3(256), dim3(256), 0, stream>>>(pw, wbf);
    k_fused<<<dim3(Bb), dim3(512), 0, stream>>>(x, wbf, pb, out);
}